// Round 2
// baseline (271.362 us; speedup 1.0000x reference)
//
#include <hip/hip_runtime.h>
#include <hip/hip_bf16.h>

#define DM 1024
#define SEQ 2048
#define NBATCH 4

using f32x4 = __attribute__((ext_vector_type(4))) float;
using s16x8 = __attribute__((ext_vector_type(8))) short;   // 8 bf16 in 4 VGPRs
using u16x4 = __attribute__((ext_vector_type(4))) unsigned short;
using u16x8 = __attribute__((ext_vector_type(8))) unsigned short;

__device__ __forceinline__ unsigned short f2bf(float f) {
  union { float f; unsigned u; } v; v.f = f;
  return (unsigned short)((v.u + 0x7fffu + ((v.u >> 16) & 1u)) >> 16);  // RNE
}

// async global->LDS, 16B per lane. Dest is wave-uniform base + lane*16 (linear);
// source is per-lane (pre-swizzled).
__device__ __forceinline__ void gll16(const unsigned short* g, unsigned short* l) {
  __builtin_amdgcn_global_load_lds((const __attribute__((address_space(1))) void*)g,
                                   (__attribute__((address_space(3))) void*)l,
                                   16, 0, 0);
}

// ---------------- fused prep: x->bf16 cast  +  W transpose/cast ----------------
__global__ void prep_k(const float* __restrict__ X,
                       const float* __restrict__ Wq, const float* __restrict__ Wk,
                       const float* __restrict__ Wv,
                       unsigned short* __restrict__ XB, unsigned short* __restrict__ WT) {
  __shared__ float t[32][33];
  const int b = blockIdx.x;
  if (b < 4096) {
    const int i = b * 256 + threadIdx.x;
    const f32x4* p = (const f32x4*)X;
    f32x4 a = p[2 * i], c = p[2 * i + 1];
    u16x8 o;
#pragma unroll
    for (int q = 0; q < 4; q++) { o[q] = f2bf(a[q]); o[4 + q] = f2bf(c[q]); }
    *(u16x8*)(XB + (size_t)i * 8) = o;
  } else {
    const int r2 = b - 4096;
    const int seg = r2 >> 10;
    const int rem = r2 & 1023;
    const int k0 = (rem >> 5) * 32, n0 = (rem & 31) * 32;
    const float* W = (seg == 0) ? Wq : (seg == 1) ? Wk : Wv;
    unsigned short* out = WT + (size_t)seg * DM * DM;
    const int tr = threadIdx.x >> 5, tc = threadIdx.x & 31;
#pragma unroll
    for (int p = 0; p < 4; p++) {
      int r = tr + p * 8;
      t[r][tc] = W[(size_t)(k0 + r) * DM + n0 + tc];
    }
    __syncthreads();
#pragma unroll
    for (int p = 0; p < 4; p++) {
      int r = tr + p * 8;
      out[(size_t)(n0 + r) * DM + k0 + tc] = f2bf(t[tc][r]);
    }
  }
}

// softmax-combine: fold 16 tile stats into scale table, TRANSPOSED T[t][idx].
// sv is SPLIT: 32 entries/row (2 wave-halves per tile), folded here.
__global__ void combine_k(const float* __restrict__ ms, const float* __restrict__ ss,
                          float* __restrict__ T) {
  const int idx = blockIdx.x * 256 + threadIdx.x;     // 0..8191
  const float* m = ms + (size_t)idx * 16;
  const float* s = ss + (size_t)idx * 32;
  float mv[16];
#pragma unroll
  for (int t = 0; t < 16; t++) mv[t] = m[t];
  float M = mv[0];
#pragma unroll
  for (int t = 1; t < 16; t++) M = fmaxf(M, mv[t]);
  float L = 0.f;
#pragma unroll
  for (int t = 0; t < 16; t++) L += (s[2 * t] + s[2 * t + 1]) * __expf(mv[t] - M);
  T[idx] = 1.0f;
#pragma unroll
  for (int t = 1; t < 16; t++) T[t * 8192 + idx] = __expf(mv[t - 1] - mv[t]);
  T[16 * 8192 + idx] = __expf(mv[15] - M) / L;
}

// =====================================================================
// QKV GEMM, 8-phase ring schedule (T3+T4+T5 on top of T2 swizzle)
// 256x256 tile, 512 threads (2Mx4N waves), K-step 32, 4-slot LDS ring
// per operand (128 KiB). global_load_lds direct staging (linear dest),
// PRE-SWIZZLED source; counted vmcnt(10) once per step (never 0 in
// steady state; tail 8->4->0). Grid 384 = 32 Mtiles x 12 Ntiles, XCD-
// bijective: xcd owns 4 contiguous M-tiles (A patch 2MB, L2-resident).
//
// LDS slot layout (fixes 4-way conflict of the naive row-major K=32 slot):
// two 64B rows packed per 128B line. line = row>>1 (0..127), 8 chunks of
// 16B per line: chunk c holds row parity c>>2, global k-chunk (c&3)^(line&3).
// Read of (row R, k-chunk qd): c = (R&1)*4 + (qd ^ ((R>>1)&3)).
// Per 8 consecutive fragment rows this spans all 8 chunks -> 32 banks;
// rows +8 repeat 2-way (free, m136). line*32 === 0 mod 32 banks.
// =====================================================================
__global__ __launch_bounds__(512, 2) void qkv8_k(
    const unsigned short* __restrict__ A,   // xb [8192][1024]
    const unsigned short* __restrict__ B,   // wt [3072][1024] (N x K)
    unsigned short* __restrict__ Qo, unsigned short* __restrict__ Ko,
    unsigned short* __restrict__ Vt,
    const float* __restrict__ bq, const float* __restrict__ bk,
    const float* __restrict__ bv) {
  constexpr int NKS = 32;                       // 1024 / 32
  __shared__ unsigned short lds8[65536];        // A ring 4x8192 | B ring 4x8192
  unsigned short* lA = lds8;
  unsigned short* lB = lds8 + 32768;

  const int tid = threadIdx.x;
  const int w = tid >> 6, l = tid & 63;
  const int ll = l & 15, qd = l >> 4;
  const int wm = w & 1, wn = w >> 1;            // 2 M x 4 N waves

  const int bid = blockIdx.x;
  const int xcd = bid & 7, slot = bid >> 3;     // 48 slots per XCD
  const int mt = xcd * 4 + slot / 12;
  const int nt = slot % 12;
  const int tileM = mt * 256, tileN = nt * 256;

  // ---- staging geometry: wave w covers 16 rows (w*16..+15) per 1KB segment.
  // lane l -> LDS bytes l*16 (linear) = line (l>>3) of segment, chunk (l&7).
  // Source address encodes the inverse swizzle: row = w*16 + seg*2 + (ch>>2),
  // k-chunk = (ch&3)^(seg&3).  (seg&3 == slot-line&3 since 8w === 0 mod 4.)
  const int seg = l >> 3, ch = l & 7;
  const int rowo = seg * 2 + (ch >> 2);
  const int kc = (ch & 3) ^ (seg & 3);
  const unsigned short* gA0 = A + (size_t)(tileM + w * 16 + rowo) * DM + kc * 8;
  const unsigned short* gA1 = gA0 + (size_t)128 * DM;
  const unsigned short* gB0 = B + (size_t)(tileN + w * 16 + rowo) * DM + kc * 8;
  const unsigned short* gB1 = gB0 + (size_t)128 * DM;
  const int dA0 = w * 512, dA1 = (w + 8) * 512; // wave-uniform LDS dests (shorts)

#define STAGE_A(n_) do { unsigned short* d_ = lA + ((n_) & 3) * 8192;          \
    gll16(gA0 + (size_t)(n_) * 32, d_ + dA0);                                  \
    gll16(gA1 + (size_t)(n_) * 32, d_ + dA1); } while (0)
#define STAGE_B(n_) do { unsigned short* d_ = lB + ((n_) & 3) * 8192;          \
    gll16(gB0 + (size_t)(n_) * 32, d_ + dA0);                                  \
    gll16(gB1 + (size_t)(n_) * 32, d_ + dA1); } while (0)

  // fragment read offsets within a slot (shorts): line*64 + chunk*8
  const int Ra = wm * 128 + ll;
  const int aoff = (Ra >> 1) * 64 + ((Ra & 1) * 4 + (qd ^ ((Ra >> 1) & 3))) * 8;
  const int Rb = wn * 64 + ll;
  const int boff = (Rb >> 1) * 64 + ((Rb & 1) * 4 + (qd ^ ((Rb >> 1) & 3))) * 8;
  // i*16 rows => line +8 => +512 shorts; (line&3) and parity unchanged.

  f32x4 acc[8][4];
#pragma unroll
  for (int i = 0; i < 8; i++)
#pragma unroll
    for (int j = 0; j < 4; j++) acc[i][j] = (f32x4){0.f, 0.f, 0.f, 0.f};

  // ---- prologue: issue A0,B0,A1,B1,A2,B2,B3 (14 loads/wave); vmcnt(10)
  // guarantees A0,B0 landed; 5 half-tiles stay in flight.
  STAGE_A(0); STAGE_B(0); STAGE_A(1); STAGE_B(1); STAGE_A(2); STAGE_B(2); STAGE_B(3);
  __builtin_amdgcn_sched_barrier(0);
  __builtin_amdgcn_s_waitcnt(0x0F7A);           // vmcnt(10)
  __builtin_amdgcn_sched_barrier(0);
  __builtin_amdgcn_s_barrier();
  __builtin_amdgcn_sched_barrier(0);

  for (int n = 0; n < NKS; ++n) {
    const unsigned short* sA = lA + (n & 3) * 8192;
    const unsigned short* sB = lB + (n & 3) * 8192;
    s16x8 af[4], bf[4];

    // ---------- phase 1: i-half 0 (8 ds_read_b128) + stage A(n+3) ----------
#pragma unroll
    for (int i = 0; i < 4; i++) af[i] = *(const s16x8*)&sA[aoff + i * 512];
#pragma unroll
    for (int j = 0; j < 4; j++) bf[j] = *(const s16x8*)&sB[boff + j * 512];
    if (n + 3 < NKS) STAGE_A(n + 3);            // overwrites A(n-1): freed at n-1.ph2 barrier
    __builtin_amdgcn_sched_barrier(0);
    __builtin_amdgcn_s_barrier();
    __builtin_amdgcn_s_waitcnt(0xC07F);         // lgkmcnt(0)
    __builtin_amdgcn_sched_barrier(0);
    __builtin_amdgcn_s_setprio(1);
#pragma unroll
    for (int i = 0; i < 4; i++)
#pragma unroll
      for (int j = 0; j < 4; j++)
        acc[i][j] = __builtin_amdgcn_mfma_f32_16x16x32_bf16(af[i], bf[j], acc[i][j], 0, 0, 0);
    __builtin_amdgcn_s_setprio(0);
    __builtin_amdgcn_sched_barrier(0);
    __builtin_amdgcn_s_barrier();
    __builtin_amdgcn_sched_barrier(0);

    // ---------- phase 2: i-half 1 (4 ds_read_b128) + stage B(n+4) ----------
#pragma unroll
    for (int i = 0; i < 4; i++) af[i] = *(const s16x8*)&sA[aoff + (i + 4) * 512];
    if (n + 4 < NKS) STAGE_B(n + 4);            // overwrites B(n): freed at ph1 barrier
    __builtin_amdgcn_sched_barrier(0);
    __builtin_amdgcn_s_barrier();
    __builtin_amdgcn_s_waitcnt(0xC07F);         // lgkmcnt(0)
    __builtin_amdgcn_sched_barrier(0);
    __builtin_amdgcn_s_setprio(1);
#pragma unroll
    for (int i = 0; i < 4; i++)
#pragma unroll
      for (int j = 0; j < 4; j++)
        acc[i + 4][j] = __builtin_amdgcn_mfma_f32_16x16x32_bf16(af[i], bf[j], acc[i + 4][j], 0, 0, 0);
    __builtin_amdgcn_s_setprio(0);
    // counted vmcnt: guarantees A(n+1),B(n+1) landed for next step.
    // steady: 5 half-tiles (10 loads) stay in flight; tail decays 8->4->0.
    if (n < NKS - 4)       __builtin_amdgcn_s_waitcnt(0x0F7A);  // vmcnt(10)
    else if (n == NKS - 4) __builtin_amdgcn_s_waitcnt(0x0F78);  // vmcnt(8)
    else if (n == NKS - 3) __builtin_amdgcn_s_waitcnt(0x0F74);  // vmcnt(4)
    else if (n == NKS - 2) __builtin_amdgcn_s_waitcnt(0x0F70);  // vmcnt(0)
    __builtin_amdgcn_sched_barrier(0);
    __builtin_amdgcn_s_barrier();
    __builtin_amdgcn_sched_barrier(0);
  }
#undef STAGE_A
#undef STAGE_B

  // ---------------- epilogue: bias + Q/K row-major, V transposed ----------------
  // C/D layout: col = wn*64 + j*16 + ll ; row = wm*128 + i*16 + qd*4 + r
#pragma unroll
  for (int i = 0; i < 8; i++) {
    const int gm0 = tileM + wm * 128 + i * 16 + qd * 4;
#pragma unroll
    for (int j = 0; j < 4; j++) {
      const int gn = tileN + wn * 64 + j * 16 + ll;
      const int seg2 = gn >> 10;                // block-uniform (256 | 1024)
      const int colin = gn & 1023;
      if (seg2 == 0) {
        const float bias = bq[colin];
#pragma unroll
        for (int r = 0; r < 4; r++) Qo[(size_t)(gm0 + r) * DM + colin] = f2bf(acc[i][j][r] + bias);
      } else if (seg2 == 1) {
        const float bias = bk[colin];
#pragma unroll
        for (int r = 0; r < 4; r++) Ko[(size_t)(gm0 + r) * DM + colin] = f2bf(acc[i][j][r] + bias);
      } else {                                  // V, stored transposed: Vt[b][d][s]
        const float bias = bv[colin];
        u16x4 pk;
#pragma unroll
        for (int r = 0; r < 4; r++) pk[r] = f2bf(acc[i][j][r] + bias);
        const int b = gm0 >> 11, s0 = gm0 & 2047;
        *(u16x4*)(Vt + ((size_t)((b << 10) + colin)) * SEQ + s0) = pk;
      }
    }
  }
}

// ------- bf16 NT GEMM: BMx128 tile, BK=64, reg-staged two-barrier K-loop -------
// (kept for MODE1 S-gemm + MODE2 PV; MODE0 replaced by qkv8_k above)
// XOR swizzle key=row&7: conflict-free b128 LDS r/w (0 conflicts verified).
// XCD-aware 1D grid: bid -> (xcd=bid&7, slot=bid>>3); per-XCD private patch.
// MODE 1 (BM=128): S-gemm + split-softmax epilogue.
// MODE 2 (BM=64): telescoped PV; 64-row tiles double block count (TLP fix).
template <int MODE, int BM, int LDA, int LDB, int KDIM>
__global__ void gemm_nt(const unsigned short* __restrict__ A,
                        const unsigned short* __restrict__ B,
                        void* __restrict__ C0,
                        unsigned short* __restrict__ C1,
                        unsigned short* __restrict__ C2,
                        const float* __restrict__ bq,
                        const float* __restrict__ bk,
                        const float* __restrict__ bv,
                        float* __restrict__ sm,
                        float* __restrict__ sv,
                        const float* __restrict__ Tt) {
  constexpr int ASTEPS = BM / 32;                 // staging steps for A (B fixed 4)
  constexpr int NJ = (BM == 128) ? 4 : 2;         // j-fragments per wave
  constexpr int WNOFF = 16 * NJ;                  // wave n-span
  __shared__ unsigned short lbuf[(BM + 128) * 64];  // A | B halves
  __shared__ float fred[256];                     // MODE1 stats exchange

  const int tid = threadIdx.x;
  const int w = tid >> 6;
  const int L = tid & 63;
  const int wm = (BM == 128) ? (w & 1) : 0;
  const int wn = (BM == 128) ? (w >> 1) : w;
  const int qd = L >> 4, ll = L & 15;

  // ---- XCD-aware tile mapping ----
  const int bid = blockIdx.x;
  const int xcd = bid & 7, slot = bid >> 3;
  int bz, tileM, tileN, nT;
  if (MODE == 1) {
    bz = xcd >> 1;
    const int mh = xcd & 1;
    const int nloc = slot & 15, mloc = slot >> 4; // 128 slots
    tileM = (mh * 8 + mloc) * 128; tileN = nloc * 128; nT = nloc;
  } else {
    bz = xcd >> 1;
    const int mh = xcd & 1;                       // M-half (16 x 64-row tiles)
    const int nloc = slot & 7, mloc = slot >> 3;  // 128 slots
    tileM = (mh * 16 + mloc) * 64; tileN = nloc * 128; nT = nloc;
  }
  (void)nT;

  const unsigned short* Ab = A;
  const unsigned short* Bb = B;
  if (MODE == 1) { Ab += (size_t)bz * SEQ * DM; Bb += (size_t)bz * SEQ * DM; }
  if (MODE == 2) { Ab += (size_t)bz * SEQ * SEQ; Bb += (size_t)bz * DM * SEQ; }

  // staging geometry: thread t -> row srow=t>>3 (0..31, +32*step), phys chunk
  // t&7, global chunk = (t&7) ^ (row&7).
  const int srow = tid >> 3;
  const int pch = tid & 7;
  const int gch = pch ^ (srow & 7);
  const unsigned short* gA = Ab + (size_t)(tileM + srow) * LDA + gch * 8;
  const unsigned short* gB = Bb + (size_t)(tileN + srow) * LDB + gch * 8;
  unsigned short* lA = lbuf;
  unsigned short* lB = lbuf + BM * 64;
  unsigned short* wAp = &lA[srow * 64 + pch * 8];
  unsigned short* wBp = &lB[srow * 64 + pch * 8];

  u16x8 rA[ASTEPS], rB[4];
#define LOADT(kt) do {                                                         \
    const size_t kk_ = (size_t)(kt) * 64;                                      \
    _Pragma("unroll")                                                          \
    for (int i_ = 0; i_ < ASTEPS; i_++)                                        \
      rA[i_] = *(const u16x8*)(gA + (size_t)i_ * 32 * LDA + kk_);              \
    _Pragma("unroll")                                                          \
    for (int i_ = 0; i_ < 4; i_++)                                             \
      rB[i_] = *(const u16x8*)(gB + (size_t)i_ * 32 * LDB + kk_);              \
  } while (0)
#define WRITET() do {                                                          \
    _Pragma("unroll")                                                          \
    for (int i_ = 0; i_ < ASTEPS; i_++) *(u16x8*)(wAp + i_ * 32 * 64) = rA[i_];\
    _Pragma("unroll")                                                          \
    for (int i_ = 0; i_ < 4; i_++)      *(u16x8*)(wBp + i_ * 32 * 64) = rB[i_];\
  } while (0)

  f32x4 acc[4][NJ];
#pragma unroll
  for (int i = 0; i < 4; i++)
#pragma unroll
    for (int j = 0; j < NJ; j++) acc[i][j] = (f32x4){0.f, 0.f, 0.f, 0.f};

  const int sw = L & 7;         // swizzle key for fragment rows

  // MODE2: prefetched scale-table values (broadcast-coalesced layout)
  float tTn[4][4];
  const float* Tb = nullptr;
  if (MODE == 2) {
    Tb = Tt + (size_t)bz * SEQ + tileM;           // wm==0 for BM=64
#pragma unroll
    for (int i = 0; i < 4; i++)
#pragma unroll
      for (int r = 0; r < 4; r++) tTn[i][r] = Tb[1 * 8192 + i * 16 + qd * 4 + r];
  }

  constexpr int NK = KDIM / 64;
  LOADT(0);
  WRITET();                      // vmcnt wait (one-time preamble exposure)
  __syncthreads();

  for (int k = 0; k < NK; ++k) {
    if (MODE == 2 && k >= 2 && (k & 1) == 0) {
      // tile boundary t=k/2: rescale acc by T[t] (in tTn), prefetch T[t+1]
#pragma unroll
      for (int i = 0; i < 4; i++)
#pragma unroll
        for (int j = 0; j < NJ; j++)
#pragma unroll
          for (int r = 0; r < 4; r++) acc[i][j][r] *= tTn[i][r];
      const int tn = (k >> 1) + 1;
#pragma unroll
      for (int i = 0; i < 4; i++)
#pragma unroll
        for (int r = 0; r < 4; r++) tTn[i][r] = Tb[(size_t)tn * 8192 + i * 16 + qd * 4 + r];
    }

    if (k + 1 < NK) LOADT(k + 1);     // global->VGPR, flies across compute

#pragma unroll
    for (int s = 0; s < 2; s++) {     // two K=32 halves of the BK=64 tile
      const int pc = ((s * 4 + qd) ^ sw) * 8;
      s16x8 av[4], bv4[NJ];
#pragma unroll
      for (int i = 0; i < 4; i++)
        av[i] = *(const s16x8*)&lA[(wm * 64 + i * 16 + ll) * 64 + pc];
#pragma unroll
      for (int j = 0; j < NJ; j++)
        bv4[j] = *(const s16x8*)&lB[(wn * WNOFF + j * 16 + ll) * 64 + pc];
#pragma unroll
      for (int i = 0; i < 4; i++)
#pragma unroll
        for (int j = 0; j < NJ; j++)
          acc[i][j] = __builtin_amdgcn_mfma_f32_16x16x32_bf16(av[i], bv4[j], acc[i][j], 0, 0, 0);
    }

    if (k + 1 < NK) {
      __builtin_amdgcn_s_waitcnt(0xC07F);       // lgkmcnt(0) only; vmem in flight
      __builtin_amdgcn_sched_barrier(0);
      __builtin_amdgcn_s_barrier();
      __builtin_amdgcn_sched_barrier(0);
      WRITET();                                  // vmcnt wait auto-inserted here
      __syncthreads();
    }
  }
#undef LOADT
#undef WRITET

  // ---------------- epilogues ----------------
  // C/D layout: col = wn*WNOFF + j*16 + ll ; row = wm*64 + i*16 + qd*4 + r
  if (MODE == 1) {
    __syncthreads();                       // sync0: all K-loop LDS reads done
    // scale by 1/32; per-wave (64-col) row max via shfl
    float mt[4][4];
#pragma unroll
    for (int i = 0; i < 4; i++)
#pragma unroll
      for (int r = 0; r < 4; r++) {
#pragma unroll
        for (int j = 0; j < NJ; j++) acc[i][j][r] *= 0.03125f;
        float v = fmaxf(fmaxf(acc[i][0][r], acc[i][1][r]), fmaxf(acc[i][2][r], acc[i][3][r]));
#pragma unroll
        for (int m = 1; m < 16; m <<= 1) v = fmaxf(v, __shfl_xor(v, m, 16));
        mt[i][r] = v;
      }
    if (ll == 0) {
#pragma unroll
      for (int i = 0; i < 4; i++)
#pragma unroll
        for (int r = 0; r < 4; r++)
          fred[wn * 128 + wm * 64 + i * 16 + qd * 4 + r] = mt[i][r];
    }
    __syncthreads();                       // sync1: fred complete
#pragma unroll
    for (int i = 0; i < 4; i++)
#pragma unroll
      for (int r = 0; r < 4; r++) {
        const int row = wm * 64 + i * 16 + qd * 4 + r;
        mt[i][r] = fmaxf(fred[row], fred[128 + row]);
      }
    // exp; P' bf16 into lbuf (swizzled); per-wave partial sums straight to sv
#pragma unroll
    for (int i = 0; i < 4; i++)
#pragma unroll
      for (int r = 0; r < 4; r++) {
        const int row = wm * 64 + i * 16 + qd * 4 + r;
        float s = 0.f;
#pragma unroll
        for (int j = 0; j < NJ; j++) {
          float e = __expf(acc[i][j][r] - mt[i][r]);
          s += e;
          const int col = wn * WNOFF + j * 16 + ll;
          lbuf[row * 128 + ((((col >> 4) ^ (row & 7)) << 4) | (col & 15))] = f2bf(e);
        }
#pragma unroll
        for (int m = 1; m < 16; m <<= 1) s += __shfl_xor(s, m, 16);
        if (ll == 0) {
          const size_t base = (size_t)bz * SEQ + tileM + row;
          sv[base * 32 + nT * 2 + wn] = s;
          if (wn == 0) sm[base * 16 + nT] = mt[i][r];
        }
      }
    __syncthreads();                       // sync2: lbuf complete
    // coalesced P' store: 8 x u16x8 per thread
    unsigned short* P = (unsigned short*)C0 + (size_t)bz * SEQ * SEQ;
#pragma unroll
    for (int p = 0; p < 8; p++) {
      const int c = p * 256 + tid;
      const int row = c >> 4, cg = c & 15;
      const int phys = ((((cg >> 1) ^ (row & 7)) << 4) | ((cg & 1) << 3));
      u16x8 val = *(const u16x8*)&lbuf[row * 128 + phys];
      *(u16x8*)(P + (size_t)(tileM + row) * SEQ + tileN + cg * 8) = val;
    }
  } else if (MODE == 2) {
    // final scale T[16] (in tTn), store fp32
    float* O = (float*)C0 + (size_t)bz * SEQ * DM;
#pragma unroll
    for (int i = 0; i < 4; i++) {
      const int gm0 = tileM + i * 16 + qd * 4;         // wm==0
#pragma unroll
      for (int j = 0; j < NJ; j++) {
        const int gn = tileN + wn * WNOFF + j * 16 + ll;
#pragma unroll
        for (int r = 0; r < 4; r++)
          O[(size_t)(gm0 + r) * DM + gn] = acc[i][j][r] * tTn[i][r];
      }
    }
  }
  (void)bq; (void)bk; (void)bv; (void)C1; (void)C2;
}

// ---------------- launch ----------------
// ws layout (bytes):
//   xb  @ 0         : 16 MB   bf16 x       [8192,1024]
//   wt  @ 16777216  :  6 MB   bf16 W^T     [3072,1024]
//   qb  @ 23068672  : 16 MB   bf16 Q       [8192,1024]
//   kb  @ 39845888  : 16 MB   bf16 K       [8192,1024]
//   vt  @ 56623104  : 16 MB   bf16 V^T     [4][1024][2048]
//   P   @ 73400320  : 32 MB   bf16 P'      [4][2048][2048]
//   ms  @ 106954752 : 512 KB  fp32 stats m [4][2048][16]
//   ss  @ 107479040 : 1 MB    fp32 stats s [4][2048][32]  (split per wave-half)
//   T   @ 108527616 : 544 KB  fp32 scale   [17][4*2048]   (transposed)
// total ~109 MB
extern "C" void kernel_launch(void* const* d_in, const int* in_sizes, int n_in,
                              void* d_out, int out_size, void* d_ws, size_t ws_size,
                              hipStream_t stream) {
  (void)in_sizes; (void)n_in; (void)out_size; (void)ws_size;
  const float* x  = (const float*)d_in[0];
  const float* Wq = (const float*)d_in[1];
  const float* bq = (const float*)d_in[2];
  const float* Wk = (const float*)d_in[3];
  const float* bk = (const float*)d_in[4];
  const float* Wv = (const float*)d_in[5];
  const float* bv = (const float*)d_in[6];
  float* out = (float*)d_out;
  char* ws = (char*)d_ws;
  unsigned short* xb = (unsigned short*)(ws + 0);
  unsigned short* wt = (unsigned short*)(ws + 16777216);
  unsigned short* qb = (unsigned short*)(ws + 23068672);
  unsigned short* kb = (unsigned short*)(ws + 39845888);
  unsigned short* vt = (unsigned short*)(ws + 56623104);
  unsigned short* P  = (unsigned short*)(ws + 73400320);
  float*          ms = (float*)(ws + 106954752);
  float*          ss = (float*)(ws + 107479040);
  float*          Tt = (float*)(ws + 108527616);

  prep_k<<<7168, 256, 0, stream>>>(x, Wq, Wk, Wv, xb, wt);
  qkv8_k<<<384, 512, 0, stream>>>(xb, wt, qb, kb, vt, bq, bk, bv);
  gemm_nt<1, 128, 1024, 1024, 1024><<<1024, 256, 0, stream>>>(
      qb, kb, (void*)P, nullptr, nullptr, nullptr, nullptr, nullptr, ms, ss, nullptr);
  combine_k<<<32, 256, 0, stream>>>(ms, ss, Tt);
  gemm_nt<2, 64, 2048, 2048, 2048><<<1024, 256, 0, stream>>>(
      P, vt, (void*)out, nullptr, nullptr, nullptr, nullptr, nullptr, nullptr, nullptr, Tt);
}

// Round 3
// 249.117 us; speedup vs baseline: 1.0893x; 1.0893x over previous
//
#include <hip/hip_runtime.h>
#include <hip/hip_bf16.h>

#define DM 1024
#define SEQ 2048
#define NBATCH 4

using f32x4 = __attribute__((ext_vector_type(4))) float;
using s16x8 = __attribute__((ext_vector_type(8))) short;   // 8 bf16 in 4 VGPRs
using u16x4 = __attribute__((ext_vector_type(4))) unsigned short;
using u16x8 = __attribute__((ext_vector_type(8))) unsigned short;

__device__ __forceinline__ unsigned short f2bf(float f) {
  union { float f; unsigned u; } v; v.f = f;
  return (unsigned short)((v.u + 0x7fffu + ((v.u >> 16) & 1u)) >> 16);  // RNE
}

// async global->LDS, 16B per lane. Dest is wave-uniform base + lane*16 (linear);
// source is per-lane (pre-swizzled).
__device__ __forceinline__ void gll16(const unsigned short* g, unsigned short* l) {
  __builtin_amdgcn_global_load_lds((const __attribute__((address_space(1))) void*)g,
                                   (__attribute__((address_space(3))) void*)l,
                                   16, 0, 0);
}

// ---------------- fused prep: x->bf16 cast  +  W transpose/cast ----------------
__global__ void prep_k(const float* __restrict__ X,
                       const float* __restrict__ Wq, const float* __restrict__ Wk,
                       const float* __restrict__ Wv,
                       unsigned short* __restrict__ XB, unsigned short* __restrict__ WT) {
  __shared__ float t[32][33];
  const int b = blockIdx.x;
  if (b < 4096) {
    const int i = b * 256 + threadIdx.x;
    const f32x4* p = (const f32x4*)X;
    f32x4 a = p[2 * i], c = p[2 * i + 1];
    u16x8 o;
#pragma unroll
    for (int q = 0; q < 4; q++) { o[q] = f2bf(a[q]); o[4 + q] = f2bf(c[q]); }
    *(u16x8*)(XB + (size_t)i * 8) = o;
  } else {
    const int r2 = b - 4096;
    const int seg = r2 >> 10;
    const int rem = r2 & 1023;
    const int k0 = (rem >> 5) * 32, n0 = (rem & 31) * 32;
    const float* W = (seg == 0) ? Wq : (seg == 1) ? Wk : Wv;
    unsigned short* out = WT + (size_t)seg * DM * DM;
    const int tr = threadIdx.x >> 5, tc = threadIdx.x & 31;
#pragma unroll
    for (int p = 0; p < 4; p++) {
      int r = tr + p * 8;
      t[r][tc] = W[(size_t)(k0 + r) * DM + n0 + tc];
    }
    __syncthreads();
#pragma unroll
    for (int p = 0; p < 4; p++) {
      int r = tr + p * 8;
      out[(size_t)(n0 + r) * DM + k0 + tc] = f2bf(t[tc][r]);
    }
  }
}

// softmax-combine: fold 16 tile stats into scale table, TRANSPOSED T[t][idx].
// sv is SPLIT: 32 entries/row (2 wave-halves per tile), folded here.
__global__ void combine_k(const float* __restrict__ ms, const float* __restrict__ ss,
                          float* __restrict__ T) {
  const int idx = blockIdx.x * 256 + threadIdx.x;     // 0..8191
  const float* m = ms + (size_t)idx * 16;
  const float* s = ss + (size_t)idx * 32;
  float mv[16];
#pragma unroll
  for (int t = 0; t < 16; t++) mv[t] = m[t];
  float M = mv[0];
#pragma unroll
  for (int t = 1; t < 16; t++) M = fmaxf(M, mv[t]);
  float L = 0.f;
#pragma unroll
  for (int t = 0; t < 16; t++) L += (s[2 * t] + s[2 * t + 1]) * __expf(mv[t] - M);
  T[idx] = 1.0f;
#pragma unroll
  for (int t = 1; t < 16; t++) T[t * 8192 + idx] = __expf(mv[t - 1] - mv[t]);
  T[16 * 8192 + idx] = __expf(mv[15] - M) / L;
}

// =====================================================================
// QKV GEMM v2: single-barrier software-pipelined ring schedule.
// 256x128 tile, 512 threads (4M x 2N waves), K-step 32, 4-slot LDS ring
// (A 16KB + B 8KB per slot = 96 KiB total). Grid 768 = 32 Mt x 24 Nt =
// 3 EXACT rounds of 256 blocks (fixes r2's 1.5-round imbalance).
//
// Per K32 step n (ONE s_barrier, counted vmcnt AND counted lgkmcnt):
//   vmcnt(3)        -> own stage(n+1) glls retired (slot n+1 landed)
//   s_barrier       -> collective: all waves' stage(n+1) retired AND all
//                      waves' reads(n-1) retired (via their prior lgkm(8))
//   issue reads(n+1) [8 ds_read_b128, reg double-buffer]
//   issue stage(n+3) [3 gll16 into slot n-1: WAR-safe per barrier above]
//   lgkmcnt(8)      -> reads(n) done; reads(n+1) STILL IN FLIGHT
//   sched_barrier(0); setprio(1); 16 MFMA on reads(n); setprio(0)
// Reads(n+1)+staging execute UNDER the MFMA cluster (the overlap r2's
// 4-barrier lockstep lacked). LDS ops retire in-order (no SMEM in loop).
//
// LDS slot layout (conflict-free, measured 0 in r2): 2 rows per 128B
// line; chunk c of line L holds row parity c>>2, k-chunk (c&3)^(L&3).
// gll dest is linear (lane*16B); source pre-swizzled (involution).
// =====================================================================
__global__ __launch_bounds__(512, 2) void qkv8_k(
    const unsigned short* __restrict__ A,   // xb [8192][1024]
    const unsigned short* __restrict__ B,   // wt [3072][1024] (N x K)
    unsigned short* __restrict__ Qo, unsigned short* __restrict__ Ko,
    unsigned short* __restrict__ Vt,
    const float* __restrict__ bq, const float* __restrict__ bk,
    const float* __restrict__ bv) {
  constexpr int NKS = 32;                       // 1024 / 32
  __shared__ unsigned short lds8[49152];        // A ring 4x8192 | B ring 4x4096
  unsigned short* lA = lds8;
  unsigned short* lB = lds8 + 32768;

  const int tid = threadIdx.x;
  const int w = tid >> 6, l = tid & 63;
  const int ll = l & 15, qd = l >> 4;
  const int wm = w >> 1, wn = w & 1;            // 4 M x 2 N waves

  const int bid = blockIdx.x;
  const int xcd = bid & 7, slot = bid >> 3;     // 96 slots per XCD
  const int mt = xcd * 4 + slot / 24;           // 4 M-tiles per XCD (A 2MB, L2)
  const int nt = slot % 24;
  const int tileM = mt * 256, tileN = nt * 128;

  // ---- staging geometry: lane l -> LDS bytes l*16 (linear) = line (l>>3),
  // chunk (l&7) of an 8-line span. Source encodes the inverse swizzle:
  // row_in_span = seg*2 + (ch>>2), k-chunk = (ch&3)^(seg&3).
  // Spans start at line multiples of 8 -> line&3 == seg&3.
  const int seg = l >> 3, ch = l & 7;
  const int rowo = seg * 2 + (ch >> 2);
  const int kc = (ch & 3) ^ (seg & 3);
  // wave w: A rows w*32..+31 (two 16-row glls), B rows w*16..+15 (one gll)
  const unsigned short* gA0 = A + (size_t)(tileM + w * 32 + rowo) * DM + kc * 8;
  const unsigned short* gB0 = B + (size_t)(tileN + w * 16 + rowo) * DM + kc * 8;
  const int dA0 = w * 1024, dB0 = w * 512;      // wave-uniform LDS dests (shorts)

#define STAGE(np) do {                                                         \
    unsigned short* dA_ = lA + ((np) & 3) * 8192 + dA0;                        \
    unsigned short* dB_ = lB + ((np) & 3) * 4096 + dB0;                        \
    const size_t ko_ = (size_t)(np) * 32;                                      \
    gll16(gA0 + ko_, dA_);                                                     \
    gll16(gA0 + (size_t)16 * DM + ko_, dA_ + 512);                             \
    gll16(gB0 + ko_, dB_);                                                     \
  } while (0)

  // fragment read offsets within a slot (shorts): line*64 + chunk*8.
  // Row R, k-chunk qd -> chunk (R&1)*4 + (qd ^ ((R>>1)&3)). +16 rows = +512.
  const int Ra = wm * 64 + ll;
  const int aoff = (Ra >> 1) * 64 + ((Ra & 1) * 4 + (qd ^ ((Ra >> 1) & 3))) * 8;
  const int Rb = wn * 64 + ll;
  const int boff = (Rb >> 1) * 64 + ((Rb & 1) * 4 + (qd ^ ((Rb >> 1) & 3))) * 8;

#define RDSET(AF, BF, np) do {                                                 \
    const unsigned short* sA_ = lA + ((np) & 3) * 8192;                        \
    const unsigned short* sB_ = lB + ((np) & 3) * 4096;                        \
    _Pragma("unroll")                                                          \
    for (int i_ = 0; i_ < 4; i_++) AF[i_] = *(const s16x8*)&sA_[aoff + i_ * 512]; \
    _Pragma("unroll")                                                          \
    for (int j_ = 0; j_ < 4; j_++) BF[j_] = *(const s16x8*)&sB_[boff + j_ * 512]; \
  } while (0)

  f32x4 acc[4][4];
#pragma unroll
  for (int i = 0; i < 4; i++)
#pragma unroll
    for (int j = 0; j < 4; j++) acc[i][j] = (f32x4){0.f, 0.f, 0.f, 0.f};

  s16x8 af0[4], bf0[4], af1[4], bf1[4];

  // ---- prologue: stage slots 0..2 (9 glls); slot0 landed -> reads(0).
  STAGE(0); STAGE(1); STAGE(2);
  __builtin_amdgcn_sched_barrier(0);
  __builtin_amdgcn_s_waitcnt(0x0F76);           // vmcnt(6): stage(0) retired
  __builtin_amdgcn_sched_barrier(0);
  __builtin_amdgcn_s_barrier();
  __builtin_amdgcn_sched_barrier(0);
  RDSET(af0, bf0, 0);

#define PIPE_STEP(n_, CA, CB, NA, NB) do {                                     \
    if ((n_) <= NKS - 3) {                                                     \
      __builtin_amdgcn_s_waitcnt(0x0F73);       /* vmcnt(3) */                 \
    } else if ((n_) == NKS - 2) {                                              \
      __builtin_amdgcn_s_waitcnt(0x0F70);       /* vmcnt(0) */                 \
    }                                                                          \
    if ((n_) <= NKS - 2) {                                                     \
      __builtin_amdgcn_sched_barrier(0);                                       \
      __builtin_amdgcn_s_barrier();                                            \
      __builtin_amdgcn_sched_barrier(0);                                       \
    }                                                                          \
    if ((n_) + 1 < NKS) RDSET(NA, NB, (n_) + 1);                               \
    if ((n_) + 3 < NKS) STAGE((n_) + 3);                                       \
    __builtin_amdgcn_sched_barrier(0);                                         \
    if ((n_) + 1 < NKS) __builtin_amdgcn_s_waitcnt(0xC87F); /* lgkmcnt(8) */   \
    else                __builtin_amdgcn_s_waitcnt(0xC07F); /* lgkmcnt(0) */   \
    __builtin_amdgcn_sched_barrier(0);                                         \
    __builtin_amdgcn_s_setprio(1);                                             \
    _Pragma("unroll")                                                          \
    for (int i_ = 0; i_ < 4; i_++)                                             \
      _Pragma("unroll")                                                        \
      for (int j_ = 0; j_ < 4; j_++)                                           \
        acc[i_][j_] = __builtin_amdgcn_mfma_f32_16x16x32_bf16(                 \
            CA[i_], CB[j_], acc[i_][j_], 0, 0, 0);                             \
    __builtin_amdgcn_s_setprio(0);                                             \
    __builtin_amdgcn_sched_barrier(0);                                         \
  } while (0)

#pragma unroll
  for (int n = 0; n < NKS; n += 2) {
    PIPE_STEP(n, af0, bf0, af1, bf1);
    PIPE_STEP(n + 1, af1, bf1, af0, bf0);
  }
#undef PIPE_STEP
#undef RDSET
#undef STAGE

  // ---------------- epilogue: bias + Q/K row-major, V transposed ----------------
  // C/D layout: col = wn*64 + j*16 + ll ; row = wm*64 + i*16 + qd*4 + r
#pragma unroll
  for (int i = 0; i < 4; i++) {
    const int gm0 = tileM + wm * 64 + i * 16 + qd * 4;
#pragma unroll
    for (int j = 0; j < 4; j++) {
      const int gn = tileN + wn * 64 + j * 16 + ll;
      const int seg2 = gn >> 10;                // block-uniform (128 | 1024)
      const int colin = gn & 1023;
      if (seg2 == 0) {
        const float bias = bq[colin];
#pragma unroll
        for (int r = 0; r < 4; r++) Qo[(size_t)(gm0 + r) * DM + colin] = f2bf(acc[i][j][r] + bias);
      } else if (seg2 == 1) {
        const float bias = bk[colin];
#pragma unroll
        for (int r = 0; r < 4; r++) Ko[(size_t)(gm0 + r) * DM + colin] = f2bf(acc[i][j][r] + bias);
      } else {                                  // V, stored transposed: Vt[b][d][s]
        const float bias = bv[colin];
        u16x4 pk;
#pragma unroll
        for (int r = 0; r < 4; r++) pk[r] = f2bf(acc[i][j][r] + bias);
        const int b = gm0 >> 11, s0 = gm0 & 2047;
        *(u16x4*)(Vt + ((size_t)((b << 10) + colin)) * SEQ + s0) = pk;
      }
    }
  }
}

// ------- bf16 NT GEMM: BMx128 tile, BK=64, reg-staged two-barrier K-loop -------
// (kept for MODE1 S-gemm + MODE2 PV)
// XOR swizzle key=row&7: conflict-free b128 LDS r/w (0 conflicts verified).
// XCD-aware 1D grid: bid -> (xcd=bid&7, slot=bid>>3); per-XCD private patch.
// MODE 1 (BM=128): S-gemm + split-softmax epilogue.
// MODE 2 (BM=64): telescoped PV; 64-row tiles double block count (TLP fix).
template <int MODE, int BM, int LDA, int LDB, int KDIM>
__global__ void gemm_nt(const unsigned short* __restrict__ A,
                        const unsigned short* __restrict__ B,
                        void* __restrict__ C0,
                        unsigned short* __restrict__ C1,
                        unsigned short* __restrict__ C2,
                        const float* __restrict__ bq,
                        const float* __restrict__ bk,
                        const float* __restrict__ bv,
                        float* __restrict__ sm,
                        float* __restrict__ sv,
                        const float* __restrict__ Tt) {
  constexpr int ASTEPS = BM / 32;                 // staging steps for A (B fixed 4)
  constexpr int NJ = (BM == 128) ? 4 : 2;         // j-fragments per wave
  constexpr int WNOFF = 16 * NJ;                  // wave n-span
  __shared__ unsigned short lbuf[(BM + 128) * 64];  // A | B halves
  __shared__ float fred[256];                     // MODE1 stats exchange

  const int tid = threadIdx.x;
  const int w = tid >> 6;
  const int L = tid & 63;
  const int wm = (BM == 128) ? (w & 1) : 0;
  const int wn = (BM == 128) ? (w >> 1) : w;
  const int qd = L >> 4, ll = L & 15;

  // ---- XCD-aware tile mapping ----
  const int bid = blockIdx.x;
  const int xcd = bid & 7, slot = bid >> 3;
  int bz, tileM, tileN, nT;
  if (MODE == 1) {
    bz = xcd >> 1;
    const int mh = xcd & 1;
    const int nloc = slot & 15, mloc = slot >> 4; // 128 slots
    tileM = (mh * 8 + mloc) * 128; tileN = nloc * 128; nT = nloc;
  } else {
    bz = xcd >> 1;
    const int mh = xcd & 1;                       // M-half (16 x 64-row tiles)
    const int nloc = slot & 7, mloc = slot >> 3;  // 128 slots
    tileM = (mh * 16 + mloc) * 64; tileN = nloc * 128; nT = nloc;
  }
  (void)nT;

  const unsigned short* Ab = A;
  const unsigned short* Bb = B;
  if (MODE == 1) { Ab += (size_t)bz * SEQ * DM; Bb += (size_t)bz * SEQ * DM; }
  if (MODE == 2) { Ab += (size_t)bz * SEQ * SEQ; Bb += (size_t)bz * DM * SEQ; }

  // staging geometry: thread t -> row srow=t>>3 (0..31, +32*step), phys chunk
  // t&7, global chunk = (t&7) ^ (row&7).
  const int srow = tid >> 3;
  const int pch = tid & 7;
  const int gch = pch ^ (srow & 7);
  const unsigned short* gA = Ab + (size_t)(tileM + srow) * LDA + gch * 8;
  const unsigned short* gB = Bb + (size_t)(tileN + srow) * LDB + gch * 8;
  unsigned short* lA = lbuf;
  unsigned short* lB = lbuf + BM * 64;
  unsigned short* wAp = &lA[srow * 64 + pch * 8];
  unsigned short* wBp = &lB[srow * 64 + pch * 8];

  u16x8 rA[ASTEPS], rB[4];
#define LOADT(kt) do {                                                         \
    const size_t kk_ = (size_t)(kt) * 64;                                      \
    _Pragma("unroll")                                                          \
    for (int i_ = 0; i_ < ASTEPS; i_++)                                        \
      rA[i_] = *(const u16x8*)(gA + (size_t)i_ * 32 * LDA + kk_);              \
    _Pragma("unroll")                                                          \
    for (int i_ = 0; i_ < 4; i_++)                                             \
      rB[i_] = *(const u16x8*)(gB + (size_t)i_ * 32 * LDB + kk_);              \
  } while (0)
#define WRITET() do {                                                          \
    _Pragma("unroll")                                                          \
    for (int i_ = 0; i_ < ASTEPS; i_++) *(u16x8*)(wAp + i_ * 32 * 64) = rA[i_];\
    _Pragma("unroll")                                                          \
    for (int i_ = 0; i_ < 4; i_++)      *(u16x8*)(wBp + i_ * 32 * 64) = rB[i_];\
  } while (0)

  f32x4 acc[4][NJ];
#pragma unroll
  for (int i = 0; i < 4; i++)
#pragma unroll
    for (int j = 0; j < NJ; j++) acc[i][j] = (f32x4){0.f, 0.f, 0.f, 0.f};

  const int sw = L & 7;         // swizzle key for fragment rows

  // MODE2: prefetched scale-table values (broadcast-coalesced layout)
  float tTn[4][4];
  const float* Tb = nullptr;
  if (MODE == 2) {
    Tb = Tt + (size_t)bz * SEQ + tileM;           // wm==0 for BM=64
#pragma unroll
    for (int i = 0; i < 4; i++)
#pragma unroll
      for (int r = 0; r < 4; r++) tTn[i][r] = Tb[1 * 8192 + i * 16 + qd * 4 + r];
  }

  constexpr int NK = KDIM / 64;
  LOADT(0);
  WRITET();                      // vmcnt wait (one-time preamble exposure)
  __syncthreads();

  for (int k = 0; k < NK; ++k) {
    if (MODE == 2 && k >= 2 && (k & 1) == 0) {
      // tile boundary t=k/2: rescale acc by T[t] (in tTn), prefetch T[t+1]
#pragma unroll
      for (int i = 0; i < 4; i++)
#pragma unroll
        for (int j = 0; j < NJ; j++)
#pragma unroll
          for (int r = 0; r < 4; r++) acc[i][j][r] *= tTn[i][r];
      const int tn = (k >> 1) + 1;
#pragma unroll
      for (int i = 0; i < 4; i++)
#pragma unroll
        for (int r = 0; r < 4; r++) tTn[i][r] = Tb[(size_t)tn * 8192 + i * 16 + qd * 4 + r];
    }

    if (k + 1 < NK) LOADT(k + 1);     // global->VGPR, flies across compute

#pragma unroll
    for (int s = 0; s < 2; s++) {     // two K=32 halves of the BK=64 tile
      const int pc = ((s * 4 + qd) ^ sw) * 8;
      s16x8 av[4], bv4[NJ];
#pragma unroll
      for (int i = 0; i < 4; i++)
        av[i] = *(const s16x8*)&lA[(wm * 64 + i * 16 + ll) * 64 + pc];
#pragma unroll
      for (int j = 0; j < NJ; j++)
        bv4[j] = *(const s16x8*)&lB[(wn * WNOFF + j * 16 + ll) * 64 + pc];
#pragma unroll
      for (int i = 0; i < 4; i++)
#pragma unroll
        for (int j = 0; j < NJ; j++)
          acc[i][j] = __builtin_amdgcn_mfma_f32_16x16x32_bf16(av[i], bv4[j], acc[i][j], 0, 0, 0);
    }

    if (k + 1 < NK) {
      __builtin_amdgcn_s_waitcnt(0xC07F);       // lgkmcnt(0) only; vmem in flight
      __builtin_amdgcn_sched_barrier(0);
      __builtin_amdgcn_s_barrier();
      __builtin_amdgcn_sched_barrier(0);
      WRITET();                                  // vmcnt wait auto-inserted here
      __syncthreads();
    }
  }
#undef LOADT
#undef WRITET

  // ---------------- epilogues ----------------
  // C/D layout: col = wn*WNOFF + j*16 + ll ; row = wm*64 + i*16 + qd*4 + r
  if (MODE == 1) {
    __syncthreads();                       // sync0: all K-loop LDS reads done
    // scale by 1/32; per-wave (64-col) row max via shfl
    float mt[4][4];
#pragma unroll
    for (int i = 0; i < 4; i++)
#pragma unroll
      for (int r = 0; r < 4; r++) {
#pragma unroll
        for (int j = 0; j < NJ; j++) acc[i][j][r] *= 0.03125f;
        float v = fmaxf(fmaxf(acc[i][0][r], acc[i][1][r]), fmaxf(acc[i][2][r], acc[i][3][r]));
#pragma unroll
        for (int m = 1; m < 16; m <<= 1) v = fmaxf(v, __shfl_xor(v, m, 16));
        mt[i][r] = v;
      }
    if (ll == 0) {
#pragma unroll
      for (int i = 0; i < 4; i++)
#pragma unroll
        for (int r = 0; r < 4; r++)
          fred[wn * 128 + wm * 64 + i * 16 + qd * 4 + r] = mt[i][r];
    }
    __syncthreads();                       // sync1: fred complete
#pragma unroll
    for (int i = 0; i < 4; i++)
#pragma unroll
      for (int r = 0; r < 4; r++) {
        const int row = wm * 64 + i * 16 + qd * 4 + r;
        mt[i][r] = fmaxf(fred[row], fred[128 + row]);
      }
    // exp; P' bf16 into lbuf (swizzled); per-wave partial sums straight to sv
#pragma unroll
    for (int i = 0; i < 4; i++)
#pragma unroll
      for (int r = 0; r < 4; r++) {
        const int row = wm * 64 + i * 16 + qd * 4 + r;
        float s = 0.f;
#pragma unroll
        for (int j = 0; j < NJ; j++) {
          float e = __expf(acc[i][j][r] - mt[i][r]);
          s += e;
          const int col = wn * WNOFF + j * 16 + ll;
          lbuf[row * 128 + ((((col >> 4) ^ (row & 7)) << 4) | (col & 15))] = f2bf(e);
        }
#pragma unroll
        for (int m = 1; m < 16; m <<= 1) s += __shfl_xor(s, m, 16);
        if (ll == 0) {
          const size_t base = (size_t)bz * SEQ + tileM + row;
          sv[base * 32 + nT * 2 + wn] = s;
          if (wn == 0) sm[base * 16 + nT] = mt[i][r];
        }
      }
    __syncthreads();                       // sync2: lbuf complete
    // coalesced P' store: 8 x u16x8 per thread
    unsigned short* P = (unsigned short*)C0 + (size_t)bz * SEQ * SEQ;
#pragma unroll
    for (int p = 0; p < 8; p++) {
      const int c = p * 256 + tid;
      const int row = c >> 4, cg = c & 15;
      const int phys = ((((cg >> 1) ^ (row & 7)) << 4) | ((cg & 1) << 3));
      u16x8 val = *(const u16x8*)&lbuf[row * 128 + phys];
      *(u16x8*)(P + (size_t)(tileM + row) * SEQ + tileN + cg * 8) = val;
    }
  } else if (MODE == 2) {
    // final scale T[16] (in tTn), store fp32
    float* O = (float*)C0 + (size_t)bz * SEQ * DM;
#pragma unroll
    for (int i = 0; i < 4; i++) {
      const int gm0 = tileM + i * 16 + qd * 4;         // wm==0
#pragma unroll
      for (int j = 0; j < NJ; j++) {
        const int gn = tileN + wn * WNOFF + j * 16 + ll;
#pragma unroll
        for (int r = 0; r < 4; r++)
          O[(size_t)(gm0 + r) * DM + gn] = acc[i][j][r] * tTn[i][r];
      }
    }
  }
  (void)bq; (void)bk; (void)bv; (void)C1; (void)C2;
}

// ---------------- launch ----------------
// ws layout (bytes):
//   xb  @ 0         : 16 MB   bf16 x       [8192,1024]
//   wt  @ 16777216  :  6 MB   bf16 W^T     [3072,1024]
//   qb  @ 23068672  : 16 MB   bf16 Q       [8192,1024]
//   kb  @ 39845888  : 16 MB   bf16 K       [8192,1024]
//   vt  @ 56623104  : 16 MB   bf16 V^T     [4][1024][2048]
//   P   @ 73400320  : 32 MB   bf16 P'      [4][2048][2048]
//   ms  @ 106954752 : 512 KB  fp32 stats m [4][2048][16]
//   ss  @ 107479040 : 1 MB    fp32 stats s [4][2048][32]  (split per wave-half)
//   T   @ 108527616 : 544 KB  fp32 scale   [17][4*2048]   (transposed)
// total ~109 MB
extern "C" void kernel_launch(void* const* d_in, const int* in_sizes, int n_in,
                              void* d_out, int out_size, void* d_ws, size_t ws_size,
                              hipStream_t stream) {
  (void)in_sizes; (void)n_in; (void)out_size; (void)ws_size;
  const float* x  = (const float*)d_in[0];
  const float* Wq = (const float*)d_in[1];
  const float* bq = (const float*)d_in[2];
  const float* Wk = (const float*)d_in[3];
  const float* bk = (const float*)d_in[4];
  const float* Wv = (const float*)d_in[5];
  const float* bv = (const float*)d_in[6];
  float* out = (float*)d_out;
  char* ws = (char*)d_ws;
  unsigned short* xb = (unsigned short*)(ws + 0);
  unsigned short* wt = (unsigned short*)(ws + 16777216);
  unsigned short* qb = (unsigned short*)(ws + 23068672);
  unsigned short* kb = (unsigned short*)(ws + 39845888);
  unsigned short* vt = (unsigned short*)(ws + 56623104);
  unsigned short* P  = (unsigned short*)(ws + 73400320);
  float*          ms = (float*)(ws + 106954752);
  float*          ss = (float*)(ws + 107479040);
  float*          Tt = (float*)(ws + 108527616);

  prep_k<<<7168, 256, 0, stream>>>(x, Wq, Wk, Wv, xb, wt);
  qkv8_k<<<768, 512, 0, stream>>>(xb, wt, qb, kb, vt, bq, bk, bv);
  gemm_nt<1, 128, 1024, 1024, 1024><<<1024, 256, 0, stream>>>(
      qb, kb, (void*)P, nullptr, nullptr, nullptr, nullptr, nullptr, ms, ss, nullptr);
  combine_k<<<32, 256, 0, stream>>>(ms, ss, Tt);
  gemm_nt<2, 64, 2048, 2048, 2048><<<1024, 256, 0, stream>>>(
      P, vt, (void*)out, nullptr, nullptr, nullptr, nullptr, nullptr, nullptr, nullptr, Tt);
}